// Round 2
// baseline (131.245 us; speedup 1.0000x reference)
//
#include <hip/hip_runtime.h>
#include <hip/hip_bf16.h>
#include <cstdint>

typedef __bf16 bf16x8 __attribute__((ext_vector_type(8)));
typedef float f32x4 __attribute__((ext_vector_type(4)));

#define BROWS 4096
#define DH    1024
#define KDIM  2048   // D_IN + D_H

// ---------------- kernel 1: concat(x,h) -> bf16 xh[4096][2048] ----------------
__global__ __launch_bounds__(256) void k_concat_cast(const float* __restrict__ x,
                                                     const float* __restrict__ h,
                                                     __hip_bfloat16* __restrict__ xh) {
  int64_t idx = ((int64_t)blockIdx.x * 256 + threadIdx.x) * 8;  // 8 elems/thread
  int row = (int)(idx >> 11);
  int col = (int)(idx & 2047);
  const float* src = (col < 1024) ? (x + (int64_t)row * 1024 + col)
                                  : (h + (int64_t)row * 1024 + (col - 1024));
  float4 v0 = reinterpret_cast<const float4*>(src)[0];
  float4 v1 = reinterpret_cast<const float4*>(src)[1];
  alignas(16) __hip_bfloat16 o8[8];
  o8[0] = __float2bfloat16(v0.x); o8[1] = __float2bfloat16(v0.y);
  o8[2] = __float2bfloat16(v0.z); o8[3] = __float2bfloat16(v0.w);
  o8[4] = __float2bfloat16(v1.x); o8[5] = __float2bfloat16(v1.y);
  o8[6] = __float2bfloat16(v1.z); o8[7] = __float2bfloat16(v1.w);
  *reinterpret_cast<int4*>(xh + idx) = *reinterpret_cast<const int4*>(o8);
}

// -------- kernel 2: W_g[k][j] fp32 -> wt[n'][k] bf16, n' = (j>>4)*64 + g*16 + (j&15) --------
__global__ __launch_bounds__(256) void k_wprep(const float* __restrict__ Wf,
                                               const float* __restrict__ Wi,
                                               const float* __restrict__ Wc,
                                               const float* __restrict__ Wo,
                                               __hip_bfloat16* __restrict__ wt) {
  __shared__ float t[64][65];
  const int tid = threadIdx.x;
  const int b = blockIdx.x;       // 2048 = 4 gates * 16 jt * 32 kt
  const int g  = b & 3;
  const int jt = (b >> 2) & 15;
  const int kt = b >> 6;
  const float* W = (g == 0) ? Wf : (g == 1) ? Wi : (g == 2) ? Wc : Wo;
  const int j0 = jt << 6, k0 = kt << 6;
#pragma unroll
  for (int i = 0; i < 4; ++i) {  // read 64x64 fp32, coalesced along j
    int r = (tid >> 4) + (i << 4);
    int c = (tid & 15) << 2;
    float4 v = *reinterpret_cast<const float4*>(W + (int64_t)(k0 + r) * 1024 + j0 + c);
    t[r][c + 0] = v.x; t[r][c + 1] = v.y; t[r][c + 2] = v.z; t[r][c + 3] = v.w;
  }
  __syncthreads();
#pragma unroll
  for (int i = 0; i < 2; ++i) {  // write rows of wt (contiguous along k)
    int task = tid + (i << 8);
    int rr = task >> 3;            // local j index 0..63
    int kc = (task & 7) << 3;      // k-chunk 0,8,...,56
    int np = (((jt << 2) + (rr >> 4)) << 6) + (g << 4) + (rr & 15);
    alignas(16) __hip_bfloat16 o8[8];
#pragma unroll
    for (int e = 0; e < 8; ++e) o8[e] = __float2bfloat16(t[kc + e][rr]);
    *reinterpret_cast<int4*>(wt + (int64_t)np * KDIM + k0 + kc) =
        *reinterpret_cast<const int4*>(o8);
  }
}

// ---------------- kernel 3: fused GEMM + LSTM epilogue ----------------
__device__ __forceinline__ void gload16(const __hip_bfloat16* g, __hip_bfloat16* l) {
  __builtin_amdgcn_global_load_lds(
      (const __attribute__((address_space(1))) void*)g,
      (__attribute__((address_space(3))) void*)l, 16, 0, 0);
}

__device__ __forceinline__ float sigmoidf_(float v) { return 1.0f / (1.0f + __expf(-v)); }

__global__ __launch_bounds__(256) void k_lstm_gemm(
    const __hip_bfloat16* __restrict__ xh, const __hip_bfloat16* __restrict__ wt,
    const float* __restrict__ cin,
    const float* __restrict__ bfp, const float* __restrict__ bip,
    const float* __restrict__ bcp, const float* __restrict__ bop,
    float* __restrict__ out) {
  // 128x128 tile, BK=64, 4 waves (2x2), each wave 64x64 via 4x4 16x16x32 fragments
  __shared__ __hip_bfloat16 As[128 * 64];
  __shared__ __hip_bfloat16 Bs[128 * 64];
  const int tid  = threadIdx.x;
  const int lane = tid & 63;
  const int wid  = tid >> 6;
  const int wm = wid >> 1, wn = wid & 1;
  const int m0 = blockIdx.y << 7;
  const int n0 = blockIdx.x << 7;   // interleaved-gate column space [0,4096)

  f32x4 acc[4][4] = {};             // [mi][gate]

  // staging map: per 16B issue, 256 threads cover 32 rows x 64 cols (128B/row)
  const int srow = tid >> 3;                   // 0..31
  const int scol = (tid & 7) << 3;             // element offset 0..56
  const __hip_bfloat16* aglob = xh + (int64_t)(m0 + srow) * KDIM + scol;
  const __hip_bfloat16* bglob = wt + (int64_t)(n0 + srow) * KDIM + scol;
  __hip_bfloat16* alds = As + (wid << 9);      // per-wave 512-elem (1 KiB) slice
  __hip_bfloat16* blds = Bs + (wid << 9);

  const int frow = lane & 15;                  // fragment row/col
  const int fk   = (lane >> 4) << 3;           // k sub-offset 0,8,16,24

  for (int kt = 0; kt < KDIM; kt += 64) {
#pragma unroll
    for (int i = 0; i < 4; ++i)
      gload16(aglob + (int64_t)(i * 32) * KDIM + kt, alds + i * 2048);
#pragma unroll
    for (int i = 0; i < 4; ++i)
      gload16(bglob + (int64_t)(i * 32) * KDIM + kt, blds + i * 2048);
    __syncthreads();   // drains vmcnt(0): LDS tiles ready for all waves
#pragma unroll
    for (int kk = 0; kk < 64; kk += 32) {
      bf16x8 av[4], bv[4];
#pragma unroll
      for (int mi = 0; mi < 4; ++mi)
        av[mi] = *reinterpret_cast<const bf16x8*>(
            As + (((wm << 6) + (mi << 4) + frow) << 6) + kk + fk);
#pragma unroll
      for (int ni = 0; ni < 4; ++ni)
        bv[ni] = *reinterpret_cast<const bf16x8*>(
            Bs + (((wn << 6) + (ni << 4) + frow) << 6) + kk + fk);
#pragma unroll
      for (int mi = 0; mi < 4; ++mi)
#pragma unroll
        for (int ni = 0; ni < 4; ++ni)
          acc[mi][ni] = __builtin_amdgcn_mfma_f32_16x16x32_bf16(
              av[mi], bv[ni], acc[mi][ni], 0, 0, 0);
    }
    __syncthreads();   // before next stage overwrites
  }

  // ---- fused LSTM epilogue (fp32 outputs: h_new, h_new, c_new) ----
  const int j = ((((n0 >> 6) + wn) << 4) + frow);      // h-column in [0,1024)
  const float vbf = bfp[j], vbi = bip[j], vbc = bcp[j], vbo = bop[j];
  float* outh1 = out;
  float* outh2 = out + (int64_t)BROWS * DH;
  float* outc  = out + (int64_t)2 * BROWS * DH;
#pragma unroll
  for (int mi = 0; mi < 4; ++mi) {
    const int mbase = m0 + (wm << 6) + (mi << 4) + ((lane >> 4) << 2);
#pragma unroll
    for (int r = 0; r < 4; ++r) {
      const int m = mbase + r;
      const int64_t idx = (int64_t)m * DH + j;
      float fg = sigmoidf_(acc[mi][0][r] + vbf);
      float ig = sigmoidf_(acc[mi][1][r] + vbi);
      float cg = tanhf(acc[mi][2][r] + vbc);
      float og = sigmoidf_(acc[mi][3][r] + vbo);
      float cn = fg * cin[idx] + ig * cg;
      float hn = og * tanhf(cn);
      outh1[idx] = hn;
      outh2[idx] = hn;
      outc[idx]  = cn;
    }
  }
}

extern "C" void kernel_launch(void* const* d_in, const int* in_sizes, int n_in,
                              void* d_out, int out_size, void* d_ws, size_t ws_size,
                              hipStream_t stream) {
  const float* x  = (const float*)d_in[0];
  const float* h  = (const float*)d_in[1];
  const float* c  = (const float*)d_in[2];
  const float* Wf = (const float*)d_in[3];
  const float* bf = (const float*)d_in[4];
  const float* Wi = (const float*)d_in[5];
  const float* bi = (const float*)d_in[6];
  const float* Wc = (const float*)d_in[7];
  const float* bc = (const float*)d_in[8];
  const float* Wo = (const float*)d_in[9];
  const float* bo = (const float*)d_in[10];
  float* out = (float*)d_out;

  __hip_bfloat16* xh = (__hip_bfloat16*)d_ws;                    // 4096x2048 bf16 (16 MiB)
  __hip_bfloat16* wt = xh + (int64_t)BROWS * KDIM;               // 4096x2048 bf16 (16 MiB)

  hipLaunchKernelGGL(k_concat_cast, dim3(4096), dim3(256), 0, stream, x, h, xh);
  hipLaunchKernelGGL(k_wprep, dim3(2048), dim3(256), 0, stream, Wf, Wi, Wc, Wo, wt);
  hipLaunchKernelGGL(k_lstm_gemm, dim3(32, 32), dim3(256), 0, stream,
                     xh, wt, c, bf, bi, bc, bo, out);
}

// Round 3
// 120.490 us; speedup vs baseline: 1.0893x; 1.0893x over previous
//
#include <hip/hip_runtime.h>
#include <hip/hip_bf16.h>
#include <cstdint>

typedef __bf16 bf16x8 __attribute__((ext_vector_type(8)));
typedef float f32x4 __attribute__((ext_vector_type(4)));

#define BROWS 4096
#define DH    1024
#define KDIM  2048   // D_IN + D_H

// ---------------- fused prep: concat(x,h)->bf16 xh  +  W transpose/interleave->wt ----------------
// blocks [0,4096): concat/cast.  blocks [4096,6144): wprep.
__global__ __launch_bounds__(256) void k_prep(const float* __restrict__ x,
                                              const float* __restrict__ h,
                                              const float* __restrict__ Wf,
                                              const float* __restrict__ Wi,
                                              const float* __restrict__ Wc,
                                              const float* __restrict__ Wo,
                                              __hip_bfloat16* __restrict__ xh,
                                              __hip_bfloat16* __restrict__ wt) {
  __shared__ float t[64][65];
  const int tid = threadIdx.x;
  if (blockIdx.x < 4096) {
    // ---- concat(x,h) -> bf16 xh[4096][2048], 8 elems/thread ----
    int64_t idx = ((int64_t)blockIdx.x * 256 + tid) * 8;
    int row = (int)(idx >> 11);
    int col = (int)(idx & 2047);
    const float* src = (col < 1024) ? (x + (int64_t)row * 1024 + col)
                                    : (h + (int64_t)row * 1024 + (col - 1024));
    float4 v0 = reinterpret_cast<const float4*>(src)[0];
    float4 v1 = reinterpret_cast<const float4*>(src)[1];
    alignas(16) __hip_bfloat16 o8[8];
    o8[0] = __float2bfloat16(v0.x); o8[1] = __float2bfloat16(v0.y);
    o8[2] = __float2bfloat16(v0.z); o8[3] = __float2bfloat16(v0.w);
    o8[4] = __float2bfloat16(v1.x); o8[5] = __float2bfloat16(v1.y);
    o8[6] = __float2bfloat16(v1.z); o8[7] = __float2bfloat16(v1.w);
    *reinterpret_cast<int4*>(xh + idx) = *reinterpret_cast<const int4*>(o8);
  } else {
    // ---- W_g[k][j] fp32 -> wt[n'][k] bf16, n' = (j>>4)*64 + g*16 + (j&15) ----
    const int b = blockIdx.x - 4096;   // 2048 = 4 gates * 16 jt * 32 kt
    const int g  = b & 3;
    const int jt = (b >> 2) & 15;
    const int kt = b >> 6;
    const float* W = (g == 0) ? Wf : (g == 1) ? Wi : (g == 2) ? Wc : Wo;
    const int j0 = jt << 6, k0 = kt << 6;
#pragma unroll
    for (int i = 0; i < 4; ++i) {  // read 64x64 fp32, coalesced along j
      int r = (tid >> 4) + (i << 4);
      int c = (tid & 15) << 2;
      float4 v = *reinterpret_cast<const float4*>(W + (int64_t)(k0 + r) * 1024 + j0 + c);
      t[r][c + 0] = v.x; t[r][c + 1] = v.y; t[r][c + 2] = v.z; t[r][c + 3] = v.w;
    }
    __syncthreads();
#pragma unroll
    for (int i = 0; i < 2; ++i) {  // write rows of wt (contiguous along k)
      int task = tid + (i << 8);
      int rr = task >> 3;            // local j index 0..63
      int kc = (task & 7) << 3;      // k-chunk 0,8,...,56
      int np = (((jt << 2) + (rr >> 4)) << 6) + (g << 4) + (rr & 15);
      alignas(16) __hip_bfloat16 o8[8];
#pragma unroll
      for (int e = 0; e < 8; ++e) o8[e] = __float2bfloat16(t[kc + e][rr]);
      *reinterpret_cast<int4*>(wt + (int64_t)np * KDIM + k0 + kc) =
          *reinterpret_cast<const int4*>(o8);
    }
  }
}

// ---------------- fused GEMM + LSTM epilogue ----------------
__device__ __forceinline__ void gload16(const __hip_bfloat16* g, __hip_bfloat16* l) {
  __builtin_amdgcn_global_load_lds(
      (const __attribute__((address_space(1))) void*)g,
      (__attribute__((address_space(3))) void*)l, 16, 0, 0);
}

__device__ __forceinline__ float sigmoidf_(float v) { return 1.0f / (1.0f + __expf(-v)); }

__global__ __launch_bounds__(256) void k_lstm_gemm(
    const __hip_bfloat16* __restrict__ xh, const __hip_bfloat16* __restrict__ wt,
    const float* __restrict__ cin,
    const float* __restrict__ bfp, const float* __restrict__ bip,
    const float* __restrict__ bcp, const float* __restrict__ bop,
    float* __restrict__ out) {
  // 128x128 tile, BK=64, 4 waves (2x2), each wave 64x64 via 4x4 16x16x32 fragments.
  // T2: LDS tiles hold row r with 16B-chunk c at physical chunk (c ^ (r&7)).
  //     Staging keeps LDS dest linear (global_load_lds constraint) and pre-swizzles
  //     the GLOBAL source chunk; fragment reads apply the same XOR. 16-way -> 2-way.
  __shared__ __hip_bfloat16 As[128 * 64];
  __shared__ __hip_bfloat16 Bs[128 * 64];
  const int tid  = threadIdx.x;
  const int lane = tid & 63;
  const int wid  = tid >> 6;
  const int wm = wid >> 1, wn = wid & 1;

  // T1: bijective XCD-chunked swizzle (1024 blocks % 8 == 0).
  // XCD x owns flats [x*128, x*128+128): n-panels [x*4, x*4+4), m fastest
  // -> B panels (512KB each) stay L2-resident per XCD.
  const int bid  = blockIdx.x;
  const int flat = ((bid & 7) << 7) + (bid >> 3);
  const int m0 = (flat & 31) << 7;
  const int n0 = (flat >> 5) << 7;   // interleaved-gate column space [0,4096)

  f32x4 acc[4][4] = {};              // [mi][gate]

  // staging map: per 16B issue, 256 threads cover 32 rows x 64 cols (128B/row)
  const int srow  = tid >> 3;                        // 0..31  (row&7 == srow&7 for all issues)
  const int schunk = (tid & 7) ^ (srow & 7);         // T2 pre-swizzled source chunk
  const __hip_bfloat16* aglob = xh + (int64_t)(m0 + srow) * KDIM + (schunk << 3);
  const __hip_bfloat16* bglob = wt + (int64_t)(n0 + srow) * KDIM + (schunk << 3);
  __hip_bfloat16* alds = As + (wid << 9);            // per-wave 512-elem (1 KiB) slice
  __hip_bfloat16* blds = Bs + (wid << 9);

  const int frow = lane & 15;                        // fragment row
  const int fk   = (lane >> 4) << 3;                 // k sub-offset 0,8,16,24
  const int fxor = (frow & 7) << 3;                  // T2 read-side XOR (elements)

  for (int kt = 0; kt < KDIM; kt += 64) {
#pragma unroll
    for (int i = 0; i < 4; ++i)
      gload16(aglob + (int64_t)(i * 32) * KDIM + kt, alds + i * 2048);
#pragma unroll
    for (int i = 0; i < 4; ++i)
      gload16(bglob + (int64_t)(i * 32) * KDIM + kt, blds + i * 2048);
    __syncthreads();   // drains vmcnt(0): LDS tiles ready for all waves
#pragma unroll
    for (int kk = 0; kk < 64; kk += 32) {
      bf16x8 av[4], bv[4];
#pragma unroll
      for (int mi = 0; mi < 4; ++mi)
        av[mi] = *reinterpret_cast<const bf16x8*>(
            As + (((wm << 6) + (mi << 4) + frow) << 6) + ((kk + fk) ^ fxor));
#pragma unroll
      for (int ni = 0; ni < 4; ++ni)
        bv[ni] = *reinterpret_cast<const bf16x8*>(
            Bs + (((wn << 6) + (ni << 4) + frow) << 6) + ((kk + fk) ^ fxor));
      __builtin_amdgcn_s_setprio(1);
#pragma unroll
      for (int mi = 0; mi < 4; ++mi)
#pragma unroll
        for (int ni = 0; ni < 4; ++ni)
          acc[mi][ni] = __builtin_amdgcn_mfma_f32_16x16x32_bf16(
              av[mi], bv[ni], acc[mi][ni], 0, 0, 0);
      __builtin_amdgcn_s_setprio(0);
    }
    __syncthreads();   // before next stage overwrites
  }

  // ---- fused LSTM epilogue (fp32 outputs: h_new, h_new, c_new) ----
  const int j = ((((n0 >> 6) + wn) << 4) + frow);      // h-column in [0,1024)
  const float vbf = bfp[j], vbi = bip[j], vbc = bcp[j], vbo = bop[j];
  float* outh1 = out;
  float* outh2 = out + (int64_t)BROWS * DH;
  float* outc  = out + (int64_t)2 * BROWS * DH;
#pragma unroll
  for (int mi = 0; mi < 4; ++mi) {
    const int mbase = m0 + (wm << 6) + (mi << 4) + ((lane >> 4) << 2);
#pragma unroll
    for (int r = 0; r < 4; ++r) {
      const int m = mbase + r;
      const int64_t idx = (int64_t)m * DH + j;
      float fg = sigmoidf_(acc[mi][0][r] + vbf);
      float ig = sigmoidf_(acc[mi][1][r] + vbi);
      float cg = tanhf(acc[mi][2][r] + vbc);
      float og = sigmoidf_(acc[mi][3][r] + vbo);
      float cn = fg * cin[idx] + ig * cg;
      float hn = og * tanhf(cn);
      outh1[idx] = hn;
      outh2[idx] = hn;
      outc[idx]  = cn;
    }
  }
}

extern "C" void kernel_launch(void* const* d_in, const int* in_sizes, int n_in,
                              void* d_out, int out_size, void* d_ws, size_t ws_size,
                              hipStream_t stream) {
  const float* x  = (const float*)d_in[0];
  const float* h  = (const float*)d_in[1];
  const float* c  = (const float*)d_in[2];
  const float* Wf = (const float*)d_in[3];
  const float* bf = (const float*)d_in[4];
  const float* Wi = (const float*)d_in[5];
  const float* bi = (const float*)d_in[6];
  const float* Wc = (const float*)d_in[7];
  const float* bc = (const float*)d_in[8];
  const float* Wo = (const float*)d_in[9];
  const float* bo = (const float*)d_in[10];
  float* out = (float*)d_out;

  __hip_bfloat16* xh = (__hip_bfloat16*)d_ws;                    // 4096x2048 bf16 (16 MiB)
  __hip_bfloat16* wt = xh + (int64_t)BROWS * KDIM;               // 4096x2048 bf16 (16 MiB)

  hipLaunchKernelGGL(k_prep, dim3(6144), dim3(256), 0, stream,
                     x, h, Wf, Wi, Wc, Wo, xh, wt);
  hipLaunchKernelGGL(k_lstm_gemm, dim3(1024), dim3(256), 0, stream,
                     xh, wt, c, bf, bi, bc, bo, out);
}

// Round 4
// 88.284 us; speedup vs baseline: 1.4866x; 1.3648x over previous
//
#include <hip/hip_runtime.h>
#include <hip/hip_bf16.h>
#include <cstdint>

typedef __bf16 bf16x8 __attribute__((ext_vector_type(8)));
typedef float f32x4 __attribute__((ext_vector_type(4)));

#define BROWS 4096
#define DH    1024
#define KDIM  2048   // D_IN + D_H
#define NT    32     // K-tiles of 64

// ---------------- fused prep: concat(x,h)->bf16 xh  +  W transpose/interleave->wt ----------------
__global__ __launch_bounds__(256) void k_prep(const float* __restrict__ x,
                                              const float* __restrict__ h,
                                              const float* __restrict__ Wf,
                                              const float* __restrict__ Wi,
                                              const float* __restrict__ Wc,
                                              const float* __restrict__ Wo,
                                              __hip_bfloat16* __restrict__ xh,
                                              __hip_bfloat16* __restrict__ wt) {
  __shared__ float t[64][65];
  const int tid = threadIdx.x;
  if (blockIdx.x < 4096) {
    // concat(x,h) -> bf16 xh[4096][2048], 8 elems/thread
    int64_t idx = ((int64_t)blockIdx.x * 256 + tid) * 8;
    int row = (int)(idx >> 11);
    int col = (int)(idx & 2047);
    const float* src = (col < 1024) ? (x + (int64_t)row * 1024 + col)
                                    : (h + (int64_t)row * 1024 + (col - 1024));
    float4 v0 = reinterpret_cast<const float4*>(src)[0];
    float4 v1 = reinterpret_cast<const float4*>(src)[1];
    alignas(16) __hip_bfloat16 o8[8];
    o8[0] = __float2bfloat16(v0.x); o8[1] = __float2bfloat16(v0.y);
    o8[2] = __float2bfloat16(v0.z); o8[3] = __float2bfloat16(v0.w);
    o8[4] = __float2bfloat16(v1.x); o8[5] = __float2bfloat16(v1.y);
    o8[6] = __float2bfloat16(v1.z); o8[7] = __float2bfloat16(v1.w);
    *reinterpret_cast<int4*>(xh + idx) = *reinterpret_cast<const int4*>(o8);
  } else {
    // W_g[k][j] fp32 -> wt[n'][k] bf16, n' = (j>>4)*64 + g*16 + (j&15)
    const int b = blockIdx.x - 4096;   // 2048 = 4 gates * 16 jt * 32 kt
    const int g  = b & 3;
    const int jt = (b >> 2) & 15;
    const int kt = b >> 6;
    const float* W = (g == 0) ? Wf : (g == 1) ? Wi : (g == 2) ? Wc : Wo;
    const int j0 = jt << 6, k0 = kt << 6;
#pragma unroll
    for (int i = 0; i < 4; ++i) {
      int r = (tid >> 4) + (i << 4);
      int c = (tid & 15) << 2;
      float4 v = *reinterpret_cast<const float4*>(W + (int64_t)(k0 + r) * 1024 + j0 + c);
      t[r][c + 0] = v.x; t[r][c + 1] = v.y; t[r][c + 2] = v.z; t[r][c + 3] = v.w;
    }
    __syncthreads();
#pragma unroll
    for (int i = 0; i < 2; ++i) {
      int task = tid + (i << 8);
      int rr = task >> 3;
      int kc = (task & 7) << 3;
      int np = (((jt << 2) + (rr >> 4)) << 6) + (g << 4) + (rr & 15);
      alignas(16) __hip_bfloat16 o8[8];
#pragma unroll
      for (int e = 0; e < 8; ++e) o8[e] = __float2bfloat16(t[kc + e][rr]);
      *reinterpret_cast<int4*>(wt + (int64_t)np * KDIM + k0 + kc) =
          *reinterpret_cast<const int4*>(o8);
    }
  }
}

// ---------------- fused GEMM + LSTM epilogue: 256x256 tile, phase-split, counted vmcnt ----------------
__device__ __forceinline__ void gload16(const __hip_bfloat16* g, __hip_bfloat16* l) {
  __builtin_amdgcn_global_load_lds(
      (const __attribute__((address_space(1))) void*)g,
      (__attribute__((address_space(3))) void*)l, 16, 0, 0);
}

__device__ __forceinline__ float sig_(float v) {
  return __builtin_amdgcn_rcpf(1.0f + __expf(-v));
}
__device__ __forceinline__ float tanh_(float v) {
  return fmaf(2.0f, __builtin_amdgcn_rcpf(1.0f + __expf(-2.0f * v)), -1.0f);
}

// LDS regions (elements): parity p in {0,1}, k-half kh in {0,1}, mat A/B.
//   A(p,kh): p*32768 + kh*8192            B(p,kh): p*32768 + 16384 + kh*8192
// Each region: 256 rows x 32 elems (64 B rows), phys chunk = logical ^ ((row>>1)&3).
// Group G (= K-half index 2t+kh) lives in region (G mod 4); staged 3 phases before read.
#define STAGE(P, KH, TS)                                                               \
  do {                                                                                 \
    const int64_t gko = (int64_t)(TS) * 64 + (KH) * 32;                                \
    gload16(aG + gko,                    lds + (P) * 32768 + (KH) * 8192 + wslot);     \
    gload16(aG + gko + 128 * KDIM,       lds + (P) * 32768 + (KH) * 8192 + 4096 + wslot); \
    gload16(bG + gko,                    lds + (P) * 32768 + 16384 + (KH) * 8192 + wslot); \
    gload16(bG + gko + 128 * KDIM,       lds + (P) * 32768 + 16384 + (KH) * 8192 + 4096 + wslot); \
  } while (0)

#define PHASE(P, KH, SP, SKH, TS)                                                      \
  do {                                                                                 \
    bf16x8 av[8], bv[4];                                                               \
    _Pragma("unroll")                                                                  \
    for (int mi = 0; mi < 8; ++mi)                                                     \
      av[mi] = *reinterpret_cast<const bf16x8*>(                                       \
          lds + (P) * 32768 + (KH) * 8192 + ((wmb + mi * 16 + frow) << 5) + rx);       \
    _Pragma("unroll")                                                                  \
    for (int ni = 0; ni < 4; ++ni)                                                     \
      bv[ni] = *reinterpret_cast<const bf16x8*>(                                       \
          lds + (P) * 32768 + 16384 + (KH) * 8192 + ((wnb + ni * 16 + frow) << 5) + rx); \
    STAGE(SP, SKH, TS);                                                                \
    asm volatile("s_waitcnt vmcnt(8)" ::: "memory");                                   \
    __builtin_amdgcn_s_barrier();                                                      \
    __builtin_amdgcn_s_setprio(1);                                                     \
    _Pragma("unroll")                                                                  \
    for (int mi = 0; mi < 8; ++mi)                                                     \
      _Pragma("unroll")                                                                \
      for (int ni = 0; ni < 4; ++ni)                                                   \
        acc[mi][ni] = __builtin_amdgcn_mfma_f32_16x16x32_bf16(av[mi], bv[ni],          \
                                                              acc[mi][ni], 0, 0, 0);   \
    __builtin_amdgcn_s_setprio(0);                                                     \
    __builtin_amdgcn_s_barrier();                                                      \
  } while (0)

__global__ __launch_bounds__(512, 2) void k_lstm_gemm(
    const __hip_bfloat16* __restrict__ xh, const __hip_bfloat16* __restrict__ wt,
    const float* __restrict__ cin,
    const float* __restrict__ bfp, const float* __restrict__ bip,
    const float* __restrict__ bcp, const float* __restrict__ bop,
    float* __restrict__ out) {
  __shared__ __hip_bfloat16 lds[65536];   // 128 KiB
  const int tid  = threadIdx.x;
  const int lane = tid & 63;
  const int wid  = tid >> 6;
  const int wm = wid >> 2, wn = wid & 3;   // 2 x 4 waves; wave output = 128 x 64
  const int wmb = wm << 7, wnb = wn << 6;

  // T1: XCD-chunked bijective swizzle (256 blocks = 8 XCD x 32)
  const int bid  = blockIdx.x;
  const int flat = ((bid & 7) << 5) | (bid >> 3);
  const int m0 = (flat & 15) << 8;
  const int n0 = (flat >> 4) << 8;         // interleaved-gate column space

  f32x4 acc[8][4] = {};                    // [mi][gate]

  // staging map: per region-issue, 512 threads cover 128 rows x 4 chunks(16B)
  const int wslot = wid << 9;                            // LDS elems per wave slot
  const int cl = (((lane & 3) ^ ((lane >> 3) & 3)) << 3);  // pre-swizzled source chunk
  const __hip_bfloat16* aG = xh + (int64_t)(m0 + (wid << 4) + (lane >> 2)) * KDIM + cl;
  const __hip_bfloat16* bG = wt + (int64_t)(n0 + (wid << 4) + (lane >> 2)) * KDIM + cl;

  // fragment read map
  const int frow = lane & 15;
  const int rx   = (((lane >> 4) ^ ((frow >> 1) & 3)) << 3);  // swizzled chunk (elems)

  // prologue: groups 0,1,2  (tile0.k0, tile0.k1, tile1.k0)
  STAGE(0, 0, 0);
  STAGE(0, 1, 0);
  STAGE(1, 0, 1);
  asm volatile("s_waitcnt vmcnt(8)" ::: "memory");   // group 0 landed
  __builtin_amdgcn_s_barrier();

  for (int t = 0; t < NT; t += 2) {
    const int tA = t + 1;                       // <= NT-1 always
    const int tB = (t + 2 < NT) ? t + 2 : NT - 1;
    const int tC = (t + 3 < NT) ? t + 3 : NT - 1;
    PHASE(0, 0, 1, 1, tA);   // read t.k0   | stage (t+1).k1
    PHASE(0, 1, 0, 0, tB);   // read t.k1   | stage (t+2).k0
    PHASE(1, 0, 0, 1, tB);   // read t+1.k0 | stage (t+2).k1
    PHASE(1, 1, 1, 0, tC);   // read t+1.k1 | stage (t+3).k0
  }

  // ---- fused LSTM epilogue (fp32 outputs: h_new, h_new, c_new) ----
  const int j = (((n0 >> 6) + wn) << 4) + frow;     // h-column in [0,1024)
  const float vbf = bfp[j], vbi = bip[j], vbc = bcp[j], vbo = bop[j];
  const int q4 = (lane >> 4) << 2;
  float* outh1 = out;
  float* outh2 = out + (int64_t)BROWS * DH;
  float* outc  = out + (int64_t)2 * BROWS * DH;
#pragma unroll
  for (int mi = 0; mi < 8; ++mi) {
    const int mbase = m0 + wmb + (mi << 4) + q4;
#pragma unroll
    for (int r = 0; r < 4; ++r) {
      const int m = mbase + r;
      const int64_t idx = (int64_t)m * DH + j;
      float fg = sig_(acc[mi][0][r] + vbf);
      float ig = sig_(acc[mi][1][r] + vbi);
      float cg = tanh_(acc[mi][2][r] + vbc);
      float og = sig_(acc[mi][3][r] + vbo);
      float cn = fg * cin[idx] + ig * cg;
      float hn = og * tanh_(cn);
      outh1[idx] = hn;
      outh2[idx] = hn;
      outc[idx]  = cn;
    }
  }
}

extern "C" void kernel_launch(void* const* d_in, const int* in_sizes, int n_in,
                              void* d_out, int out_size, void* d_ws, size_t ws_size,
                              hipStream_t stream) {
  const float* x  = (const float*)d_in[0];
  const float* h  = (const float*)d_in[1];
  const float* c  = (const float*)d_in[2];
  const float* Wf = (const float*)d_in[3];
  const float* bf = (const float*)d_in[4];
  const float* Wi = (const float*)d_in[5];
  const float* bi = (const float*)d_in[6];
  const float* Wc = (const float*)d_in[7];
  const float* bc = (const float*)d_in[8];
  const float* Wo = (const float*)d_in[9];
  const float* bo = (const float*)d_in[10];
  float* out = (float*)d_out;

  __hip_bfloat16* xh = (__hip_bfloat16*)d_ws;                    // 4096x2048 bf16 (16 MiB)
  __hip_bfloat16* wt = xh + (int64_t)BROWS * KDIM;               // 4096x2048 bf16 (16 MiB)

  hipLaunchKernelGGL(k_prep, dim3(6144), dim3(256), 0, stream,
                     x, h, Wf, Wi, Wc, Wo, xh, wt);
  hipLaunchKernelGGL(k_lstm_gemm, dim3(256), dim3(512), 0, stream,
                     xh, wt, c, bf, bi, bc, bo, out);
}

// Round 7
// 86.639 us; speedup vs baseline: 1.5148x; 1.0190x over previous
//
#include <hip/hip_runtime.h>
#include <hip/hip_bf16.h>
#include <cstdint>

typedef __bf16 bf16x8 __attribute__((ext_vector_type(8)));
typedef float f32x4 __attribute__((ext_vector_type(4)));

#define BROWS 4096
#define DH    1024
#define KDIM  2048   // D_IN + D_H
#define NT    32     // K-tiles of 64

// ---------------- fused prep: concat(x,h)->bf16 xh  +  W transpose/interleave->wt ----------------
__global__ __launch_bounds__(256) void k_prep(const float* __restrict__ x,
                                              const float* __restrict__ h,
                                              const float* __restrict__ Wf,
                                              const float* __restrict__ Wi,
                                              const float* __restrict__ Wc,
                                              const float* __restrict__ Wo,
                                              __hip_bfloat16* __restrict__ xh,
                                              __hip_bfloat16* __restrict__ wt) {
  __shared__ float t[64][65];
  const int tid = threadIdx.x;
  if (blockIdx.x < 4096) {
    // concat(x,h) -> bf16 xh[4096][2048], 8 elems/thread
    int64_t idx = ((int64_t)blockIdx.x * 256 + tid) * 8;
    int row = (int)(idx >> 11);
    int col = (int)(idx & 2047);
    const float* src = (col < 1024) ? (x + (int64_t)row * 1024 + col)
                                    : (h + (int64_t)row * 1024 + (col - 1024));
    float4 v0 = reinterpret_cast<const float4*>(src)[0];
    float4 v1 = reinterpret_cast<const float4*>(src)[1];
    alignas(16) __hip_bfloat16 o8[8];
    o8[0] = __float2bfloat16(v0.x); o8[1] = __float2bfloat16(v0.y);
    o8[2] = __float2bfloat16(v0.z); o8[3] = __float2bfloat16(v0.w);
    o8[4] = __float2bfloat16(v1.x); o8[5] = __float2bfloat16(v1.y);
    o8[6] = __float2bfloat16(v1.z); o8[7] = __float2bfloat16(v1.w);
    *reinterpret_cast<int4*>(xh + idx) = *reinterpret_cast<const int4*>(o8);
  } else {
    // W_g[k][j] fp32 -> wt[n'][k] bf16, n' = (j>>4)*64 + g*16 + (j&15)
    const int b = blockIdx.x - 4096;   // 2048 = 4 gates * 16 jt * 32 kt
    const int g  = b & 3;
    const int jt = (b >> 2) & 15;
    const int kt = b >> 6;
    const float* W = (g == 0) ? Wf : (g == 1) ? Wi : (g == 2) ? Wc : Wo;
    const int j0 = jt << 6, k0 = kt << 6;
#pragma unroll
    for (int i = 0; i < 4; ++i) {
      int r = (tid >> 4) + (i << 4);
      int c = (tid & 15) << 2;
      float4 v = *reinterpret_cast<const float4*>(W + (int64_t)(k0 + r) * 1024 + j0 + c);
      t[r][c + 0] = v.x; t[r][c + 1] = v.y; t[r][c + 2] = v.z; t[r][c + 3] = v.w;
    }
    __syncthreads();
#pragma unroll
    for (int i = 0; i < 2; ++i) {
      int task = tid + (i << 8);
      int rr = task >> 3;
      int kc = (task & 7) << 3;
      int np = (((jt << 2) + (rr >> 4)) << 6) + (g << 4) + (rr & 15);
      alignas(16) __hip_bfloat16 o8[8];
#pragma unroll
      for (int e = 0; e < 8; ++e) o8[e] = __float2bfloat16(t[kc + e][rr]);
      *reinterpret_cast<int4*>(wt + (int64_t)np * KDIM + k0 + kc) =
          *reinterpret_cast<const int4*>(o8);
    }
  }
}

// ---------------- fused GEMM + LSTM epilogue: 256x256, 8-phase fine interleave ----------------
__device__ __forceinline__ float sig_(float v) {
  return __builtin_amdgcn_rcpf(1.0f + __expf(-v));
}
__device__ __forceinline__ float tanh_(float v) {
  return fmaf(2.0f, __builtin_amdgcn_rcpf(1.0f + __expf(-2.0f * v)), -1.0f);
}

// LDS regions (elements): parity p, k-half kh:  A(p,kh) = p*32768 + kh*8192 (256 rows x 32)
//                                               B(p,kh) = p*32768 + 16384 + kh*8192
// Swizzle: phys 16B-chunk = logical ^ ((row>>1)&3); stage pre-swizzles the global source,
// gload_lds dest stays linear (wave-uniform base + lane*16B), reads XOR the chunk.
// NOTE: global_load_lds imm offset applies to BOTH global and LDS address -> always 0;
//       all offsets live in the global pointer.
#define GLD(PTR, LOFF)                                                           \
  __builtin_amdgcn_global_load_lds(                                              \
      (const __attribute__((address_space(1))) void*)(PTR),                      \
      (__attribute__((address_space(3))) void*)(lds + (LOFF) + wslot), 16, 0, 0)

#define STG(P0, P1, LBASE)                                                       \
  do { GLD(P0, (LBASE)); GLD(P1, (LBASE) + 4096); } while (0)

#define LDSA(P, KH, MI)                                                          \
  (*reinterpret_cast<const bf16x8*>(lds + (P) * 32768 + (KH) * 8192 + abase + (MI) * 512))
#define LDSB(P, KH, NI)                                                          \
  (*reinterpret_cast<const bf16x8*>(lds + (P) * 32768 + (KH) * 8192 + bbase + (NI) * 512))

#define VM4 asm volatile("s_waitcnt vmcnt(4)" ::: "memory")
#define NOVM do {} while (0)

#define PHASE(P, KH, MIH, STAGE_STMT, VMSTMT)                                    \
  do {                                                                           \
    bf16x8 av[4];                                                                \
    if ((MIH) == 0) {                                                            \
      _Pragma("unroll") for (int ni = 0; ni < 4; ++ni) bv[ni] = LDSB(P, KH, ni); \
    }                                                                            \
    _Pragma("unroll") for (int i = 0; i < 4; ++i) av[i] = LDSA(P, KH, (MIH) * 4 + i); \
    STAGE_STMT;                                                                  \
    VMSTMT;                                                                      \
    __builtin_amdgcn_s_barrier();                                                \
    __builtin_amdgcn_s_setprio(1);                                               \
    _Pragma("unroll") for (int i = 0; i < 4; ++i)                                \
      _Pragma("unroll") for (int ni = 0; ni < 4; ++ni)                           \
        acc[(MIH) * 4 + i][ni] = __builtin_amdgcn_mfma_f32_16x16x32_bf16(        \
            av[i], bv[ni], acc[(MIH) * 4 + i][ni], 0, 0, 0);                     \
    __builtin_amdgcn_s_setprio(0);                                               \
    __builtin_amdgcn_s_barrier();                                                \
  } while (0)

#define ADV do { a0 += 64; a1 += 64; b0 += 64; b1 += 64; } while (0)

__global__ __launch_bounds__(512, 2) void k_lstm_gemm(
    const __hip_bfloat16* __restrict__ xh, const __hip_bfloat16* __restrict__ wt,
    const float* __restrict__ cin,
    const float* __restrict__ bfp, const float* __restrict__ bip,
    const float* __restrict__ bcp, const float* __restrict__ bop,
    float* __restrict__ out) {
  __shared__ __hip_bfloat16 lds[65536];   // 128 KiB
  const int tid  = threadIdx.x;
  const int lane = tid & 63;
  const int wid  = tid >> 6;
  const int wm = wid >> 2, wn = wid & 3;   // 2 x 4 waves; wave output = 128 x 64
  const int wmb = wm << 7, wnb = wn << 6;

  // T1: XCD-chunked bijective swizzle (256 blocks = 8 XCD x 32)
  const int bid  = blockIdx.x;
  const int flat = ((bid & 7) << 5) | (bid >> 3);
  const int m0 = (flat & 15) << 8;
  const int n0 = (flat >> 4) << 8;         // interleaved-gate column space

  f32x4 acc[8][4] = {};                    // [mi][gate]

  // ---- staging addressing: 512 thr x 16B = 128 rows x 4 chunks per GLD ----
  // LDS dest wave-uniform (global_load_lds writes base + lane*16B).
  const int wslot = wid << 9;                                 // elems; lane l lands at tid*16B
  const int cl = (((lane & 3) ^ ((lane >> 3) & 3)) << 3);     // pre-swizzled source chunk
  const __hip_bfloat16* a0 = xh + (int64_t)(m0 + (tid >> 2)) * KDIM + cl;
  const __hip_bfloat16* a1 = a0 + 128 * KDIM;
  const __hip_bfloat16* b0 = wt + (int64_t)(n0 + (tid >> 2)) * KDIM + cl;
  const __hip_bfloat16* b1 = b0 + 128 * KDIM;

  // ---- fragment read bases (lane-constant) ----
  const int frow = lane & 15;
  const int rx   = (((lane >> 4) ^ ((frow >> 1) & 3)) << 3);  // swizzled chunk (elems)
  const int abase = ((wmb + frow) << 5) + rx;
  const int bbase = 16384 + ((wnb + frow) << 5) + rx;

  // ---- prologue: stage tile0 U1..U4 (8 loads); land U1,U2 ----
  STG(a0, a1, 0);                          // t0 U1: A(0,0)
  STG(b0, b1, 16384);                      // t0 U2: B(0,0)
  STG(a0 + 32, a1 + 32, 8192);             // t0 U3: A(0,1)  (k-half 1 via pointer +32)
  STG(b0 + 32, b1 + 32, 16384 + 8192);     // t0 U4: B(0,1)
  ADV;                                     // pointers -> k=64 (tile1)
  asm volatile("s_waitcnt vmcnt(4)" ::: "memory");
  __builtin_amdgcn_s_barrier();

  for (int t = 0; t < NT; t += 2) {
    {  // tile t (parity 0): stage tile t+1 into parity 1
      bf16x8 bv[4];
      PHASE(0, 0, 0, STG(a0, a1, 32768), NOVM);
      PHASE(0, 0, 1, STG(b0, b1, 32768 + 16384), VM4);
      PHASE(0, 1, 0, STG(a0 + 32, a1 + 32, 32768 + 8192), NOVM);
      PHASE(0, 1, 1, STG(b0 + 32, b1 + 32, 32768 + 16384 + 8192), VM4);
    }
    if (t != 30) ADV;
    {  // tile t+1 (parity 1): stage tile t+2 into parity 0 (t=30: dead re-stage, in-bounds)
      bf16x8 bv[4];
      PHASE(1, 0, 0, STG(a0, a1, 0), NOVM);
      PHASE(1, 0, 1, STG(b0, b1, 16384), VM4);
      PHASE(1, 1, 0, STG(a0 + 32, a1 + 32, 8192), NOVM);
      PHASE(1, 1, 1, STG(b0 + 32, b1 + 32, 16384 + 8192), VM4);
    }
    ADV;
  }

  // ---- fused LSTM epilogue (fp32 outputs: h_new, h_new, c_new) ----
  const int j = (((n0 >> 6) + wn) << 4) + frow;     // h-column in [0,1024)
  const float vbf = bfp[j], vbi = bip[j], vbc = bcp[j], vbo = bop[j];
  const int q4 = (lane >> 4) << 2;
  float* outh1 = out;
  float* outh2 = out + (int64_t)BROWS * DH;
  float* outc  = out + (int64_t)2 * BROWS * DH;
#pragma unroll
  for (int mi = 0; mi < 8; ++mi) {
    const int mbase = m0 + wmb + (mi << 4) + q4;
#pragma unroll
    for (int r = 0; r < 4; ++r) {
      const int m = mbase + r;
      const int64_t idx = (int64_t)m * DH + j;
      float fg = sig_(acc[mi][0][r] + vbf);
      float ig = sig_(acc[mi][1][r] + vbi);
      float cg = tanh_(acc[mi][2][r] + vbc);
      float og = sig_(acc[mi][3][r] + vbo);
      float cn = fg * cin[idx] + ig * cg;
      float hn = og * tanh_(cn);
      outh1[idx] = hn;
      outh2[idx] = hn;
      outc[idx]  = cn;
    }
  }
}

extern "C" void kernel_launch(void* const* d_in, const int* in_sizes, int n_in,
                              void* d_out, int out_size, void* d_ws, size_t ws_size,
                              hipStream_t stream) {
  const float* x  = (const float*)d_in[0];
  const float* h  = (const float*)d_in[1];
  const float* c  = (const float*)d_in[2];
  const float* Wf = (const float*)d_in[3];
  const float* bf = (const float*)d_in[4];
  const float* Wi = (const float*)d_in[5];
  const float* bi = (const float*)d_in[6];
  const float* Wc = (const float*)d_in[7];
  const float* bc = (const float*)d_in[8];
  const float* Wo = (const float*)d_in[9];
  const float* bo = (const float*)d_in[10];
  float* out = (float*)d_out;

  __hip_bfloat16* xh = (__hip_bfloat16*)d_ws;                    // 4096x2048 bf16 (16 MiB)
  __hip_bfloat16* wt = xh + (int64_t)BROWS * KDIM;               // 4096x2048 bf16 (16 MiB)

  hipLaunchKernelGGL(k_prep, dim3(6144), dim3(256), 0, stream,
                     x, h, Wf, Wi, Wc, Wo, xh, wt);
  hipLaunchKernelGGL(k_lstm_gemm, dim3(256), dim3(512), 0, stream,
                     xh, wt, c, bf, bi, bc, bo, out);
}